// Round 7
// baseline (904.545 us; speedup 1.0000x reference)
//
#include <hip/hip_runtime.h>
#include <stdint.h>
#include <math.h>

#define TOKENS 8192
#define DMODEL 2048
#define HID    8192

// Block tile: 128 tokens (BM) x 256 B-rows (BR), BK=64 bytes.
// 8 waves (2M x 4N), wave tile 64x64 via mfma_i32_32x32x32_i8:
// acc[2][2] x 16 = 64 AGPR -> <=128 regs/thread.
// 3-deep LDS pipeline (3 x 24KB = 72KB) -> 2 blocks/CU (16 waves), counted vmcnt.
#define TILE_B 24576

typedef __attribute__((ext_vector_type(4))) int v4i;
typedef __attribute__((ext_vector_type(16))) int v16i;

typedef const __attribute__((address_space(1))) uint32_t gu32;
typedef __attribute__((address_space(3))) uint32_t lu32;

__device__ __forceinline__ void gload16(const void* g, void* l) {
  // async global->LDS DMA; dest = wave-uniform base + lane*16
  __builtin_amdgcn_global_load_lds((gu32*)g, (lu32*)l, 16, 0, 0);
}

// ---------------- weight absmean: partial |w| sums (fp64) ----------------
__global__ __launch_bounds__(256) void k_abssum(const float* __restrict__ w, long long n4,
                                                double* __restrict__ partial) {
  long long i0 = (long long)blockIdx.x * 256 + threadIdx.x;
  long long stride = (long long)gridDim.x * 256;
  const float4* w4 = (const float4*)w;
  double s = 0.0;
  for (long long i = i0; i < n4; i += stride) {
    float4 v = w4[i];
    s += (double)fabsf(v.x) + (double)fabsf(v.y) + (double)fabsf(v.z) + (double)fabsf(v.w);
  }
  __shared__ double sm[256];
  sm[threadIdx.x] = s;
  __syncthreads();
  for (int off = 128; off > 0; off >>= 1) {
    if ((int)threadIdx.x < off) sm[threadIdx.x] += sm[threadIdx.x + off];
    __syncthreads();
  }
  if (threadIdx.x == 0) partial[blockIdx.x] = sm[0];
}

// ---------------- finalize: s = max(mean|w|, 1e-5) for both weights ----------------
__global__ __launch_bounds__(256) void k_finalize(const double* __restrict__ pg, int ng, double cg,
                                                  const double* __restrict__ po, int no, double co,
                                                  float* __restrict__ scales) {
  __shared__ double sm[256];
  int tid = threadIdx.x;
  double s = 0.0;
  for (int i = tid; i < ng; i += 256) s += pg[i];
  sm[tid] = s; __syncthreads();
  for (int off = 128; off > 0; off >>= 1) { if (tid < off) sm[tid] += sm[tid + off]; __syncthreads(); }
  if (tid == 0) scales[0] = (float)fmax(sm[0] / cg, 1e-5);
  __syncthreads();
  s = 0.0;
  for (int i = tid; i < no; i += 256) s += po[i];
  sm[tid] = s; __syncthreads();
  for (int off = 128; off > 0; off >>= 1) { if (tid < off) sm[tid] += sm[tid + off]; __syncthreads(); }
  if (tid == 0) scales[1] = (float)fmax(sm[0] / co, 1e-5);
}

// ---------------- ternary weight quant: q = clip(rint(w/s), -1, 1) ----------------
__global__ __launch_bounds__(256) void k_wquant(const float* __restrict__ w, long long n4,
                                                const float* __restrict__ sptr,
                                                uint8_t* __restrict__ q) {
  long long i = (long long)blockIdx.x * 256 + threadIdx.x;
  if (i >= n4) return;
  float s = *sptr;
  float4 v = ((const float4*)w)[i];
  int q0 = (int)rintf(v.x / s); q0 = q0 < -1 ? -1 : (q0 > 1 ? 1 : q0);
  int q1 = (int)rintf(v.y / s); q1 = q1 < -1 ? -1 : (q1 > 1 ? 1 : q1);
  int q2 = (int)rintf(v.z / s); q2 = q2 < -1 ? -1 : (q2 > 1 ? 1 : q2);
  int q3 = (int)rintf(v.w / s); q3 = q3 < -1 ? -1 : (q3 > 1 ? 1 : q3);
  uint32_t packed = (uint32_t)(q0 & 0xff) | ((uint32_t)(q1 & 0xff) << 8) |
                    ((uint32_t)(q2 & 0xff) << 16) | ((uint32_t)(q3 & 0xff) << 24);
  ((uint32_t*)q)[i] = packed;
}

__device__ __forceinline__ int q127(float a) {
  float r = rintf(a);
  r = fminf(fmaxf(r, -127.0f), 127.0f);
  return (int)r;
}

// ---------------- fused RMSNorm + per-token int8 quant ----------------
__global__ __launch_bounds__(256) void k_rmsnorm_quant(const float* __restrict__ x,
                                                       const float* __restrict__ g,
                                                       uint8_t* __restrict__ a1,
                                                       float* __restrict__ d1) {
  int t = blockIdx.x;
  int tid = threadIdx.x;
  const float4* xr = (const float4*)(x + (long long)t * DMODEL);
  const float4* gr = (const float4*)g;
  float4 xv[2], gv[2];
  xv[0] = xr[tid]; xv[1] = xr[tid + 256];
  gv[0] = gr[tid]; gv[1] = gr[tid + 256];
  double ss = 0.0;
  for (int p = 0; p < 2; p++) {
    float4 v = xv[p];
    ss += (double)v.x * v.x + (double)v.y * v.y + (double)v.z * v.z + (double)v.w * v.w;
  }
  int lane = tid & 63, wave = tid >> 6;
  for (int off = 32; off > 0; off >>= 1) ss += __shfl_down(ss, off);
  __shared__ double wsum[4];
  if (lane == 0) wsum[wave] = ss;
  __syncthreads();
  double var = (wsum[0] + wsum[1] + wsum[2] + wsum[3]) / (double)DMODEL;
  float r = (float)(1.0 / sqrt(var + 1e-5));
  float h[8];
  h[0] = xv[0].x * r * gv[0].x; h[1] = xv[0].y * r * gv[0].y;
  h[2] = xv[0].z * r * gv[0].z; h[3] = xv[0].w * r * gv[0].w;
  h[4] = xv[1].x * r * gv[1].x; h[5] = xv[1].y * r * gv[1].y;
  h[6] = xv[1].z * r * gv[1].z; h[7] = xv[1].w * r * gv[1].w;
  float am = 0.f;
  for (int k = 0; k < 8; k++) am = fmaxf(am, fabsf(h[k]));
  for (int off = 32; off > 0; off >>= 1) am = fmaxf(am, __shfl_down(am, off));
  __shared__ float wmax[4];
  if (lane == 0) wmax[wave] = am;
  __syncthreads();
  float amc = fmaxf(fmaxf(fmaxf(wmax[0], wmax[1]), fmaxf(wmax[2], wmax[3])), 1e-5f);
  float scale = 127.0f / amc;
  uint32_t* arow = (uint32_t*)(a1 + (long long)t * DMODEL);
  for (int p = 0; p < 2; p++) {
    int q0 = q127(h[p * 4 + 0] * scale);
    int q1 = q127(h[p * 4 + 1] * scale);
    int q2 = q127(h[p * 4 + 2] * scale);
    int q3 = q127(h[p * 4 + 3] * scale);
    arow[tid + p * 256] = (uint32_t)(q0 & 0xff) | ((uint32_t)(q1 & 0xff) << 8) |
                          ((uint32_t)(q2 & 0xff) << 16) | ((uint32_t)(q3 & 0xff) << 24);
  }
  if (tid == 0) d1[t] = amc / 127.0f;
}

// ================= shared K-loop: 3-deep pipeline, counted vmcnt, 32x32x32 MFMA =================
// Per tile per wave: 8 ds_read_b128 (4 A-frags + 4 B-frags over 2 k-subtiles), 8 MFMAs.
// Fragment addressing: row = base + (lane&31); global k-slot g = (subtile*2 + lane>>5);
// LDS slot = g ^ ((rl>>1)&3)  [the SAME involution the staging pre-applies to the source].
// Octet bank check: 8 consecutive lanes hit all 32 banks exactly once -> conflict-free.
// vmcnt(3) leaves t+2's loads in flight (never drain in steady state).
template<int NT>
__device__ __forceinline__ void kloop(const uint8_t* srcA, const uint8_t* srcB0,
                                      const uint8_t* srcB1, uint8_t* smem,
                                      int w, int lane, v16i (&acc)[2][2]) {
  int ldsA = w * 1024;
  int ldsB = 8192 + w * 2048;
  // prologue: stage tiles 0 and 1
  gload16(srcA,       smem + ldsA);
  gload16(srcB0,      smem + ldsB);
  gload16(srcB1,      smem + ldsB + 1024);
  gload16(srcA + 64,  smem + TILE_B + ldsA);
  gload16(srcB0 + 64, smem + TILE_B + ldsB);
  gload16(srcB1 + 64, smem + TILE_B + ldsB + 1024);
  asm volatile("s_waitcnt vmcnt(3)" ::: "memory");   // tile 0 resident, tile 1 in flight
  __builtin_amdgcn_sched_barrier(0);
  __builtin_amdgcn_s_barrier();

  int wm = (w >> 2) * 64, wn = (w & 3) * 64;
  int rl = lane & 31, q = lane >> 5;
  int rsw = (rl >> 1) & 3;
  int sl0 = ((0 + q) ^ rsw) << 4;   // LDS slot offset holding global k-slot q      (k 0..31)
  int sl1 = ((2 + q) ^ rsw) << 4;   // LDS slot offset holding global k-slot 2+q   (k 32..63)
  int aoff = (wm + rl) * 64;        // A frag row base (e adds 2048)
  int boff = 8192 + (wn + rl) * 64; // B frag row base (j adds 2048)

  int cur = 0, nxt = 2 * TILE_B;
#pragma unroll 3
  for (int t = 0; t < NT; ++t) {
    if (t + 2 < NT) {
      int ko = (t + 2) * 64;
      gload16(srcA + ko,  smem + nxt + ldsA);
      gload16(srcB0 + ko, smem + nxt + ldsB);
      gload16(srcB1 + ko, smem + nxt + ldsB + 1024);
    }
    __builtin_amdgcn_sched_barrier(0);   // pin: prefetch issued before compute region
    const uint8_t* bT = smem + cur;
    __builtin_amdgcn_s_setprio(1);
    // k-subtile 0 frags first (first-use order), then subtile 1
    v4i a00 = *(const v4i*)(bT + aoff + sl0);
    v4i b00 = *(const v4i*)(bT + boff + sl0);
    v4i a01 = *(const v4i*)(bT + aoff + 2048 + sl0);
    v4i b01 = *(const v4i*)(bT + boff + 2048 + sl0);
    v4i a10 = *(const v4i*)(bT + aoff + sl1);
    v4i b10 = *(const v4i*)(bT + boff + sl1);
    v4i a11 = *(const v4i*)(bT + aoff + 2048 + sl1);
    v4i b11 = *(const v4i*)(bT + boff + 2048 + sl1);
    acc[0][0] = __builtin_amdgcn_mfma_i32_32x32x32_i8(a00, b00, acc[0][0], 0, 0, 0);
    acc[0][1] = __builtin_amdgcn_mfma_i32_32x32x32_i8(a00, b01, acc[0][1], 0, 0, 0);
    acc[1][0] = __builtin_amdgcn_mfma_i32_32x32x32_i8(a01, b00, acc[1][0], 0, 0, 0);
    acc[1][1] = __builtin_amdgcn_mfma_i32_32x32x32_i8(a01, b01, acc[1][1], 0, 0, 0);
    acc[0][0] = __builtin_amdgcn_mfma_i32_32x32x32_i8(a10, b10, acc[0][0], 0, 0, 0);
    acc[0][1] = __builtin_amdgcn_mfma_i32_32x32x32_i8(a10, b11, acc[0][1], 0, 0, 0);
    acc[1][0] = __builtin_amdgcn_mfma_i32_32x32x32_i8(a11, b10, acc[1][0], 0, 0, 0);
    acc[1][1] = __builtin_amdgcn_mfma_i32_32x32x32_i8(a11, b11, acc[1][1], 0, 0, 0);
    __builtin_amdgcn_s_setprio(0);
    if (t < NT - 1) {
      if (t + 2 < NT) asm volatile("s_waitcnt vmcnt(3)" ::: "memory");  // t+1 resident
      else            asm volatile("s_waitcnt vmcnt(0)" ::: "memory");  // drain tail
      __builtin_amdgcn_sched_barrier(0);
      __builtin_amdgcn_s_barrier();
    }
    cur += TILE_B; if (cur == 3 * TILE_B) cur = 0;
    nxt += TILE_B; if (nxt == 3 * TILE_B) nxt = 0;
  }
}

// ---------------- GEMM1: 128 tokens x 128 out-cols (64v+64g per N-wave pair), fused SwiGLU ----------------
__global__ __launch_bounds__(512, 4) void k_gemm1_v7(
    const uint8_t* __restrict__ A, const uint8_t* __restrict__ Bq,
    const float* __restrict__ d1, const float* __restrict__ scales,
    float* __restrict__ H2) {
  __shared__ __align__(16) uint8_t smem[3 * TILE_B];   // 72KB >= epilogue 128*132*4
  int tid = threadIdx.x, lane = tid & 63, w = tid >> 6;
  int wm = (w >> 2) * 64, wn = (w & 3) * 64;
  int rl = lane & 31, q = lane >> 5;

  // XCD-contiguous, n-fast within groups of 4 bm (A window ~1MB L2-resident)
  int bid = blockIdx.x;
  int xcd = bid & 7;
  int loc = bid >> 3;             // [0, 512)
  int g = loc >> 8;               // {0,1}
  int i5 = loc & 255;
  int bn = i5 >> 2;               // [0,64)
  int bm = xcd * 8 + g * 4 + (i5 & 3);
  long long m0 = (long long)bm * 128;
  int n0 = bn * 128;

  // staging source (pre-swizzled column = involution of read swizzle)
  int cidA = w * 64 + lane;                 // [0,512)
  int rA = cidA >> 2;
  int cA = ((cidA & 3) ^ ((rA >> 1) & 3)) << 4;
  int cidB0 = w * 128 + lane, cidB1 = cidB0 + 64;   // [0,1024)
  int rB0 = cidB0 >> 2, rB1 = cidB1 >> 2;
  int cB0 = ((cidB0 & 3) ^ ((rB0 >> 1) & 3)) << 4;
  int cB1 = ((cidB1 & 3) ^ ((rB1 >> 1) & 3)) << 4;
  const uint8_t* srcA = A + (m0 + rA) * (long long)DMODEL + cA;
  long long gr0 = (rB0 < 128) ? (long long)(n0 + rB0) : (long long)(HID + n0 + rB0 - 128);
  long long gr1 = (rB1 < 128) ? (long long)(n0 + rB1) : (long long)(HID + n0 + rB1 - 128);
  const uint8_t* srcB0 = Bq + gr0 * DMODEL + cB0;
  const uint8_t* srcB1 = Bq + gr1 * DMODEL + cB1;

  v16i acc[2][2] = {};
  kloop<DMODEL / 64>(srcA, srcB0, srcB1, smem, w, lane, acc);

  __syncthreads();   // all waves done with K-loop LDS before reuse as sil buffer

  // ---- epilogue: gate waves (wn>=128) publish silu via LDS; value waves write H2 ----
  // C/D layout (32x32): col = lane&31, row = (reg&3) + 8*(reg>>2) + 4*(lane>>5)
  float sgv = scales[0];
  float* sil = (float*)smem;      // [128 tokens][132]
  if (wn >= 128) {
#pragma unroll
    for (int e = 0; e < 2; ++e) {
#pragma unroll
      for (int j = 0; j < 2; ++j) {
#pragma unroll
        for (int r = 0; r < 16; ++r) {
          int ri = wm + e * 32 + (r & 3) + 8 * (r >> 2) + 4 * q;
          float ds = d1[m0 + ri] * sgv;
          float gg = (float)acc[e][j][r] * ds;
          sil[ri * 132 + (wn - 128) + j * 32 + rl] = gg / (1.0f + expf(-gg));
        }
      }
    }
  }
  __syncthreads();
  if (wn < 128) {
#pragma unroll
    for (int e = 0; e < 2; ++e) {
#pragma unroll
      for (int j = 0; j < 2; ++j) {
#pragma unroll
        for (int r = 0; r < 16; ++r) {
          int ri = wm + e * 32 + (r & 3) + 8 * (r >> 2) + 4 * q;
          long long token = m0 + ri;
          float ds = d1[token] * sgv;
          float v = (float)acc[e][j][r] * ds;
          H2[token * HID + n0 + wn + j * 32 + rl] = v * sil[ri * 132 + wn + j * 32 + rl];
        }
      }
    }
  }
}

// ---------------- per-token int8 quant of h2 (row of 8192) ----------------
__global__ __launch_bounds__(256) void k_hquant(const float* __restrict__ H2,
                                                uint8_t* __restrict__ A2,
                                                float* __restrict__ d2) {
  int t = blockIdx.x;
  int tid = threadIdx.x;
  const float4* hr = (const float4*)(H2 + (long long)t * HID);
  float4 v[8];
  float am = 0.f;
  for (int p = 0; p < 8; p++) {
    v[p] = hr[tid + p * 256];
    am = fmaxf(am, fmaxf(fmaxf(fabsf(v[p].x), fabsf(v[p].y)), fmaxf(fabsf(v[p].z), fabsf(v[p].w))));
  }
  int lane = tid & 63, wave = tid >> 6;
  for (int off = 32; off > 0; off >>= 1) am = fmaxf(am, __shfl_down(am, off));
  __shared__ float wmax[4];
  if (lane == 0) wmax[wave] = am;
  __syncthreads();
  float amc = fmaxf(fmaxf(fmaxf(wmax[0], wmax[1]), fmaxf(wmax[2], wmax[3])), 1e-5f);
  float scale = 127.0f / amc;
  uint32_t* arow = (uint32_t*)(A2 + (long long)t * HID);
  for (int p = 0; p < 8; p++) {
    int q0 = q127(v[p].x * scale);
    int q1 = q127(v[p].y * scale);
    int q2 = q127(v[p].z * scale);
    int q3 = q127(v[p].w * scale);
    arow[tid + p * 256] = (uint32_t)(q0 & 0xff) | ((uint32_t)(q1 & 0xff) << 8) |
                          ((uint32_t)(q2 & 0xff) << 16) | ((uint32_t)(q3 & 0xff) << 24);
  }
  if (tid == 0) d2[t] = amc / 127.0f;
}

// ---------------- GEMM2: 128 tokens x 256 d_model cols + residual ----------------
__global__ __launch_bounds__(512, 4) void k_gemm2_v7(
    const uint8_t* __restrict__ A2, const uint8_t* __restrict__ Bq,
    const float* __restrict__ d2, const float* __restrict__ scales,
    const float* __restrict__ x, float* __restrict__ out) {
  __shared__ __align__(16) uint8_t smem[3 * TILE_B];
  int tid = threadIdx.x, lane = tid & 63, w = tid >> 6;
  int wm = (w >> 2) * 64, wn = (w & 3) * 64;
  int rl = lane & 31, q = lane >> 5;

  // grid 64 x 8 = 512; per XCD 8bm x 8bn, groups of 2 bm (A window 2MB)
  int bid = blockIdx.x;
  int xcd = bid & 7;
  int loc = bid >> 3;             // [0,64)
  int g = loc >> 4;               // [0,4)
  int i5 = loc & 15;
  int bn = i5 >> 1;               // [0,8)
  int bm = xcd * 8 + g * 2 + (i5 & 1);
  long long m0 = (long long)bm * 128;
  int n0 = bn * 256;

  int cidA = w * 64 + lane;
  int rA = cidA >> 2;
  int cA = ((cidA & 3) ^ ((rA >> 1) & 3)) << 4;
  int cidB0 = w * 128 + lane, cidB1 = cidB0 + 64;
  int rB0 = cidB0 >> 2, rB1 = cidB1 >> 2;
  int cB0 = ((cidB0 & 3) ^ ((rB0 >> 1) & 3)) << 4;
  int cB1 = ((cidB1 & 3) ^ ((rB1 >> 1) & 3)) << 4;
  const uint8_t* srcA = A2 + (m0 + rA) * (long long)HID + cA;
  const uint8_t* srcB0 = Bq + (long long)(n0 + rB0) * HID + cB0;
  const uint8_t* srcB1 = Bq + (long long)(n0 + rB1) * HID + cB1;

  v16i acc[2][2] = {};
  kloop<HID / 64>(srcA, srcB0, srcB1, smem, w, lane, acc);

  float so = scales[1];
#pragma unroll
  for (int e = 0; e < 2; ++e) {
#pragma unroll
    for (int j = 0; j < 2; ++j) {
#pragma unroll
      for (int r = 0; r < 16; ++r) {
        int ri = wm + e * 32 + (r & 3) + 8 * (r >> 2) + 4 * q;
        long long token = m0 + ri;
        float ds = d2[token] * so;
        int c = n0 + wn + j * 32 + rl;
        out[token * DMODEL + c] = x[token * DMODEL + c] + (float)acc[e][j][r] * ds;
      }
    }
  }
}

extern "C" void kernel_launch(void* const* d_in, const int* in_sizes, int n_in,
                              void* d_out, int out_size, void* d_ws, size_t ws_size,
                              hipStream_t stream) {
  const float* x      = (const float*)d_in[0];
  const float* norm_w = (const float*)d_in[1];
  const float* w_gv   = (const float*)d_in[2];
  const float* w_out  = (const float*)d_in[3];
  float* out = (float*)d_out;

  char* ws = (char*)d_ws;
  size_t off = 0;
  float*   H2    = (float*)(ws + off);   off += (size_t)TOKENS * HID * 4;   // 268 MB
  uint8_t* A2    = (uint8_t*)(ws + off); off += (size_t)TOKENS * HID;       // 67 MB
  uint8_t* Wqgv  = (uint8_t*)(ws + off); off += (size_t)2 * HID * DMODEL;   // 33.5 MB
  uint8_t* Wqout = (uint8_t*)(ws + off); off += (size_t)DMODEL * HID;       // 16.8 MB
  uint8_t* A1    = (uint8_t*)(ws + off); off += (size_t)TOKENS * DMODEL;    // 16.8 MB
  float*   d1    = (float*)(ws + off);   off += (size_t)TOKENS * 4;
  float*   d2    = (float*)(ws + off);   off += (size_t)TOKENS * 4;
  double*  pgv   = (double*)(ws + off);  off += 1024 * 8;
  double*  pout  = (double*)(ws + off);  off += 512 * 8;
  float*   scales = (float*)(ws + off);  off += 16;

  const long long ngv = (long long)2 * HID * DMODEL;   // 33554432
  const long long nout = (long long)DMODEL * HID;      // 16777216

  k_abssum<<<1024, 256, 0, stream>>>(w_gv, ngv / 4, pgv);
  k_abssum<<<512, 256, 0, stream>>>(w_out, nout / 4, pout);
  k_finalize<<<1, 256, 0, stream>>>(pgv, 1024, (double)ngv, pout, 512, (double)nout, scales);
  k_wquant<<<(int)((ngv / 4 + 255) / 256), 256, 0, stream>>>(w_gv, ngv / 4, scales + 0, Wqgv);
  k_wquant<<<(int)((nout / 4 + 255) / 256), 256, 0, stream>>>(w_out, nout / 4, scales + 1, Wqout);
  k_rmsnorm_quant<<<TOKENS, 256, 0, stream>>>(x, norm_w, A1, d1);
  k_gemm1_v7<<<dim3((TOKENS / 128) * (HID / 128)), 512, 0, stream>>>(A1, Wqgv, d1, scales, H2);
  k_hquant<<<TOKENS, 256, 0, stream>>>(H2, A2, d2);
  k_gemm2_v7<<<dim3((TOKENS / 128) * (DMODEL / 256)), 512, 0, stream>>>(A2, Wqout, d2, scales, x, out);
}